// Round 6
// baseline (158.444 us; speedup 1.0000x reference)
//
#include <hip/hip_runtime.h>
#include <hip/hip_bf16.h>
#include <stdint.h>

#define S_LEN 2048
#define D_DIM 1024
#define NROW 4096

typedef __attribute__((ext_vector_type(8))) short short8;
typedef __attribute__((ext_vector_type(4))) float f32x4;
typedef __attribute__((ext_vector_type(4))) int i32x4;
typedef unsigned short ushort_t;

__device__ __forceinline__ ushort_t f2bf(float f) {
  uint32_t u = __float_as_uint(f);
  u += 0x7fffu + ((u >> 16) & 1u);
  return (ushort_t)(u >> 16);
}

__device__ __forceinline__ void gload16(const void* g, void* l) {
  __builtin_amdgcn_global_load_lds((const __attribute__((address_space(1))) void*)g,
                                   (__attribute__((address_space(3))) void*)l, 16, 0, 0);
}

// ---------------- convert fp32 -> bf16: x + Wq|Wk|Wv (contiguous) ----------
__global__ void convert4_kernel(const float* __restrict__ x,
                                const float* __restrict__ wq, const float* __restrict__ wk,
                                const float* __restrict__ wv,
                                ushort_t* __restrict__ xb, ushort_t* __restrict__ wcat) {
  const float* src; ushort_t* dst; int n;
  switch (blockIdx.y) {
    case 0: src = x;  dst = xb;             n = NROW * D_DIM;  break;
    case 1: src = wq; dst = wcat;           n = D_DIM * D_DIM; break;
    case 2: src = wk; dst = wcat + 1048576; n = D_DIM * D_DIM; break;
    default: src = wv; dst = wcat + 2097152; n = D_DIM * D_DIM; break;
  }
  int base = (blockIdx.x * 256 + threadIdx.x) * 8;
  if (base >= n) return;
  f32x4 va = *(const f32x4*)(src + base);
  f32x4 vb = *(const f32x4*)(src + base + 4);
  short8 o;
  o[0] = (short)f2bf(va[0]); o[1] = (short)f2bf(va[1]);
  o[2] = (short)f2bf(va[2]); o[3] = (short)f2bf(va[3]);
  o[4] = (short)f2bf(vb[0]); o[5] = (short)f2bf(vb[1]);
  o[6] = (short)f2bf(vb[2]); o[7] = (short)f2bf(vb[3]);
  *(short8*)(dst + base) = o;
}

__global__ void convert_wo_kernel(const float* __restrict__ wo, ushort_t* __restrict__ wob) {
  int base = (blockIdx.x * 256 + threadIdx.x) * 8;
  f32x4 va = *(const f32x4*)(wo + base);
  f32x4 vb = *(const f32x4*)(wo + base + 4);
  short8 o;
  o[0] = (short)f2bf(va[0]); o[1] = (short)f2bf(va[1]);
  o[2] = (short)f2bf(va[2]); o[3] = (short)f2bf(va[3]);
  o[4] = (short)f2bf(vb[0]); o[5] = (short)f2bf(vb[1]);
  o[6] = (short)f2bf(vb[2]); o[7] = (short)f2bf(vb[3]);
  *(short8*)(wob + base) = o;
}

// ---------------- GEMM with global_load_lds staging ------------------------
// A[4096,1024]*Bw[NB,1024]^T. MODE 0: merged QKV epilogue (NB=3072).
// MODE 2: fp32 row-major out (NB=1024).
template<int MODE>
__global__ __launch_bounds__(256, 4) void gemm_glds(const ushort_t* __restrict__ A,
                                                    const ushort_t* __restrict__ Bw,
                                                    const float* __restrict__ bias0,
                                                    const float* __restrict__ bias1,
                                                    const float* __restrict__ bias2,
                                                    void* __restrict__ Cout) {
  __shared__ ushort_t As[128 * 64];
  __shared__ ushort_t Bs[128 * 64];
  const int t = threadIdx.x;
  const int lane = t & 63;
  const int w = t >> 6;
  const int wm = w >> 1, wn = w & 1;
  const int m0 = blockIdx.x * 128, n0 = blockIdx.y * 128;
  const int g = lane >> 4, c0 = lane & 15;
  const int srow = lane >> 3, scol = (lane & 7) * 8;

  f32x4 acc[4][4] = {};

  for (int kt = 0; kt < 16; ++kt) {
    const int kk = kt * 64;
#pragma unroll
    for (int i = 0; i < 4; ++i) {
      gload16(A  + (size_t)(m0 + w * 32 + i * 8 + srow) * D_DIM + kk + scol, &As[(w * 32 + i * 8) * 64]);
      gload16(Bw + (size_t)(n0 + w * 32 + i * 8 + srow) * D_DIM + kk + scol, &Bs[(w * 32 + i * 8) * 64]);
    }
    asm volatile("s_waitcnt vmcnt(0)" ::: "memory");
    __syncthreads();
#pragma unroll
    for (int kc = 0; kc < 2; ++kc) {
      short8 af[4], bf[4];
#pragma unroll
      for (int mf = 0; mf < 4; ++mf)
        af[mf] = *(const short8*)&As[(wm * 64 + mf * 16 + c0) * 64 + kc * 32 + g * 8];
#pragma unroll
      for (int nf = 0; nf < 4; ++nf)
        bf[nf] = *(const short8*)&Bs[(wn * 64 + nf * 16 + c0) * 64 + kc * 32 + g * 8];
#pragma unroll
      for (int mf = 0; mf < 4; ++mf)
#pragma unroll
        for (int nf = 0; nf < 4; ++nf)
          acc[mf][nf] = __builtin_amdgcn_mfma_f32_16x16x32_bf16(af[mf], bf[nf], acc[mf][nf], 0, 0, 0);
    }
    __syncthreads();
  }

#pragma unroll
  for (int nf = 0; nf < 4; ++nf) {
    int jj = n0 + wn * 64 + nf * 16 + c0;
    float bval;
    if (MODE == 0) {
      int proj = jj >> 10, jcol = jj & 1023;
      const float* bp = (proj == 0) ? bias0 : ((proj == 1) ? bias1 : bias2);
      bval = bp[jcol];
    } else {
      bval = bias0[jj];
    }
#pragma unroll
    for (int mf = 0; mf < 4; ++mf) {
#pragma unroll
      for (int r = 0; r < 4; ++r) {
        int ii = m0 + wm * 64 + mf * 16 + g * 4 + r;
        float v = acc[mf][nf][r] + bval;
        if (MODE == 2) {
          ((float*)Cout)[(size_t)ii * D_DIM + jj] = v;
        } else {
          int proj = jj >> 10, jcol = jj & 1023;
          if (proj == 0) v *= 0.125f;                    // fold sm_scale into Q
          int bb = ii >> 11, s = ii & 2047;
          size_t addr;
          if (proj < 2) {
            int hcol = jcol >> 6, hd = jcol & 63;
            addr = (size_t)proj * 4194304 + ((size_t)(bb * 16 + hcol) * 2048 + s) * 64 + hd;
          } else {
            addr = (size_t)2 * 4194304 + ((size_t)bb * 1024 + jcol) * 2048 + s;   // V^T (b,h,hd,s)
          }
          ((ushort_t*)Cout)[addr] = f2bf(v);
        }
      }
    }
  }
}

// ---------------- fused masked attention -----------------------------------
// Swapped QK^T: lane holds S[k = nf*16+g*4+r][q = c0]; along r, k is
// CONTIGUOUS -> M read raw f32 as 4 x dwordx4 per iter (no transform kernel).
// P redistributed in-register via cvt_pk + 8 ds_bpermute.
// 4 waves x 16 q = 64-q tile; kv 64 single-buffered LDS (18.4KB) with T14
// split staging; grid 1024 -> 4 independent blocks/CU.
__global__ __launch_bounds__(256, 4) void attn_kernel(const ushort_t* __restrict__ Qg,
                                                      const ushort_t* __restrict__ Kg,
                                                      const ushort_t* __restrict__ Vtg,
                                                      const float* __restrict__ Mg,
                                                      ushort_t* __restrict__ aout) {
  __shared__ ushort_t Ks[64 * 72];
  __shared__ ushort_t Vts[64 * 72];

  const int t = threadIdx.x, lane = t & 63, w = t >> 6;   // 4 waves
  const int g = lane >> 4, c0 = lane & 15;
  // XCD swizzle: 16 heads of one (b,q0) group land on one XCD (id%8 dispatch)
  const int id = blockIdx.x;
  const int xcd = id & 7, j = id >> 3;
  const int hh = j & 15, gi = j >> 4;
  const int g64 = xcd + 8 * gi;             // 0..63 = b*32 + q0i
  const int b = g64 >> 5, q0 = (g64 & 31) * 64;
  const int bh = b * 16 + hh;

  const ushort_t* Qbase  = Qg  + ((size_t)bh * 2048 + q0) * 64;
  const ushort_t* Kbase  = Kg  + (size_t)bh * 2048 * 64;
  const ushort_t* Vtbase = Vtg + (size_t)bh * 64 * 2048;
  const float*    Mbase  = Mg + ((size_t)b * 2048 + q0 + w * 16 + c0) * 2048 + g * 4;

  short8 qf[2];
#pragma unroll
  for (int kc = 0; kc < 2; ++kc)
    qf[kc] = *(const short8*)(Qbase + (size_t)(w * 16 + c0) * 64 + kc * 32 + g * 8);

  f32x4 o[4] = {};
  float dpe = 0.f;
  const int idxA = (((g & 1) * 2 + (g >> 1)) * 16 + c0) * 4;
  const int idxB = (((g & 1) * 2 + 1 - (g >> 1)) * 16 + c0) * 4;
  const bool glo = (g < 2);
  const bool gb = (g & 1);

  // staging: 64x64 shorts = 512 short8 items = 2 passes of 256 threads
  short8 rk[2], rv[2];
#define A_LOAD(kt) { const int k0 = (kt) * 64; \
    _Pragma("unroll") for (int i = 0; i < 2; ++i) { int c = i * 256 + t; int row = c >> 3, c8 = (c & 7) * 8; \
      rk[i] = *(const short8*)(Kbase  + (size_t)(k0 + row) * 64 + c8); \
      rv[i] = *(const short8*)(Vtbase + (size_t)row * 2048 + k0 + c8); } }
#define A_WRITE() { \
    _Pragma("unroll") for (int i = 0; i < 2; ++i) { int c = i * 256 + t; int row = c >> 3, c8 = (c & 7) * 8; \
      *(short8*)&Ks[row * 72 + c8]  = rk[i]; \
      *(short8*)&Vts[row * 72 + c8] = rv[i]; } }

  A_LOAD(0); A_WRITE(); __syncthreads();

  for (int kt = 0; kt < 32; ++kt) {
    if (kt < 31) A_LOAD(kt + 1);      // T14: issue next-tile loads early

    // M fragment: 4 x f32x4, k contiguous along r
    f32x4 mv[4];
    {
      const float* Mk = Mbase + kt * 64;
#pragma unroll
      for (int nf = 0; nf < 4; ++nf)
        mv[nf] = *(const f32x4*)(Mk + nf * 16);
    }

    // QK^T swapped: sf[nf][r] = S[k = nf*16 + g*4 + r][q = c0]
    f32x4 sf[4] = {};
#pragma unroll
    for (int kc = 0; kc < 2; ++kc) {
      short8 kf[4];
#pragma unroll
      for (int nf = 0; nf < 4; ++nf)
        kf[nf] = *(const short8*)&Ks[(nf * 16 + c0) * 72 + kc * 32 + g * 8];
#pragma unroll
      for (int nf = 0; nf < 4; ++nf)
        sf[nf] = __builtin_amdgcn_mfma_f32_16x16x32_bf16(kf[nf], qf[kc], sf[nf], 0, 0, 0);
    }

    // mask * exp ; pack P to bf16 pairs (k-adjacent within lane)
    uint32_t w4[4][2];
#pragma unroll
    for (int nf = 0; nf < 4; ++nf) {
      float p[4];
#pragma unroll
      for (int r = 0; r < 4; ++r) {
        float m = mv[nf][r];
        float e = __expf(sf[nf][r] * m);
        float pe = m * e;
        dpe += pe;
        p[r] = pe;
      }
      asm("v_cvt_pk_bf16_f32 %0, %1, %2" : "=v"(w4[nf][0]) : "v"(p[0]), "v"(p[1]));
      asm("v_cvt_pk_bf16_f32 %0, %1, %2" : "=v"(w4[nf][1]) : "v"(p[2]), "v"(p[3]));
    }

    // redistribute: lane needs P[q=c0][k = kc*32 + g*8 + j]
    short8 pf[2];
#pragma unroll
    for (int kc = 0; kc < 2; ++kc) {
      uint32_t sA0 = gb ? w4[2 * kc + 1][0] : w4[2 * kc][0];
      uint32_t sA1 = gb ? w4[2 * kc + 1][1] : w4[2 * kc][1];
      uint32_t sB0 = gb ? w4[2 * kc][0]     : w4[2 * kc + 1][0];
      uint32_t sB1 = gb ? w4[2 * kc][1]     : w4[2 * kc + 1][1];
      uint32_t rA0 = (uint32_t)__builtin_amdgcn_ds_bpermute(idxA, (int)sA0);
      uint32_t rA1 = (uint32_t)__builtin_amdgcn_ds_bpermute(idxA, (int)sA1);
      uint32_t rB0 = (uint32_t)__builtin_amdgcn_ds_bpermute(idxB, (int)sB0);
      uint32_t rB1 = (uint32_t)__builtin_amdgcn_ds_bpermute(idxB, (int)sB1);
      i32x4 f4;
      f4[0] = (int)(glo ? rA0 : rB0);
      f4[1] = (int)(glo ? rA1 : rB1);
      f4[2] = (int)(glo ? rB0 : rA0);
      f4[3] = (int)(glo ? rB1 : rA1);
      pf[kc] = __builtin_bit_cast(short8, f4);
    }

    // PV: o^T[d][q] += sum_k V[k][d] * P[q][k]
#pragma unroll
    for (int kc = 0; kc < 2; ++kc) {
#pragma unroll
      for (int df = 0; df < 4; ++df) {
        short8 vf = *(const short8*)&Vts[(df * 16 + c0) * 72 + kc * 32 + g * 8];
        o[df] = __builtin_amdgcn_mfma_f32_16x16x32_bf16(vf, pf[kc], o[df], 0, 0, 0);
      }
    }

    __syncthreads();                   // all reads of tile kt done
    if (kt < 31) {
      A_WRITE();                       // T14: write prefetched tile kt+1
      __syncthreads();
    }
  }

  // denominator: reduce across the 4 g-groups (same q = c0)
  dpe += __shfl_xor(dpe, 16);
  dpe += __shfl_xor(dpe, 32);
  float inv = 1.0f / dpe;

  // write O^T fragment: lane has O[d = df*16 + g*4 + r][q = c0]
#pragma unroll
  for (int df = 0; df < 4; ++df) {
    float v0 = o[df][0] * inv, v1 = o[df][1] * inv;
    float v2 = o[df][2] * inv, v3 = o[df][3] * inv;
    uint32_t d0, d1;
    asm("v_cvt_pk_bf16_f32 %0, %1, %2" : "=v"(d0) : "v"(v0), "v"(v1));
    asm("v_cvt_pk_bf16_f32 %0, %1, %2" : "=v"(d1) : "v"(v2), "v"(v3));
    unsigned long long pk = (unsigned long long)d0 | ((unsigned long long)d1 << 32);
    *(unsigned long long*)&aout[((size_t)b * 2048 + q0 + w * 16 + c0) * 1024 + hh * 64 + df * 16 + g * 4] = pk;
  }
#undef A_LOAD
#undef A_WRITE
}

// ---------------------------------------------------------------------------
extern "C" void kernel_launch(void* const* d_in, const int* in_sizes, int n_in,
                              void* d_out, int out_size, void* d_ws, size_t ws_size,
                              hipStream_t stream) {
  const float* x  = (const float*)d_in[0];
  const float* M  = (const float*)d_in[1];
  const float* Wq = (const float*)d_in[2];
  const float* bq = (const float*)d_in[3];
  const float* Wk = (const float*)d_in[4];
  const float* bk = (const float*)d_in[5];
  const float* Wv = (const float*)d_in[6];
  const float* bv = (const float*)d_in[7];
  const float* Wo = (const float*)d_in[8];
  const float* bo = (const float*)d_in[9];
  float* out = (float*)d_out;
  char* ws = (char*)d_ws;

  ushort_t* Qb    = (ushort_t*)(ws);               // 8MB   [qkv-gemm .. attn]
  ushort_t* Kb    = (ushort_t*)(ws + 8388608);     // 8MB
  ushort_t* Vtb   = (ushort_t*)(ws + 16777216);    // 8MB
  ushort_t* xb    = (ushort_t*)(ws + 25165824);    // 8MB   [convert .. qkv-gemm]
  ushort_t* Wcat  = (ushort_t*)(ws + 33554432);    // 6MB   [convert .. qkv-gemm]
  ushort_t* aoutb = (ushort_t*)(ws + 41943040);    // 8MB   [attn .. out-gemm]
  ushort_t* wob   = (ushort_t*)(ws + 39845888);    // 2MB   [anytime; below aoutb]

  convert4_kernel<<<dim3(2048, 4), 256, 0, stream>>>(x, Wq, Wk, Wv, xb, Wcat);
  convert_wo_kernel<<<512, 256, 0, stream>>>(Wo, wob);
  gemm_glds<0><<<dim3(32, 24), 256, 0, stream>>>(xb, Wcat, bq, bk, bv, (void*)Qb);
  attn_kernel<<<1024, 256, 0, stream>>>(Qb, Kb, Vtb, M, aoutb);
  gemm_glds<2><<<dim3(32, 8), 256, 0, stream>>>(aoutb, wob, bo, bo, bo, (void*)out);
}

// Round 7
// 151.079 us; speedup vs baseline: 1.0487x; 1.0487x over previous
//
#include <hip/hip_runtime.h>
#include <hip/hip_bf16.h>
#include <stdint.h>

#define S_LEN 2048
#define D_DIM 1024
#define NROW 4096

typedef __attribute__((ext_vector_type(8))) short short8;
typedef __attribute__((ext_vector_type(4))) float f32x4;
typedef __attribute__((ext_vector_type(4))) int i32x4;
typedef unsigned short ushort_t;

__device__ __forceinline__ ushort_t f2bf(float f) {
  uint32_t u = __float_as_uint(f);
  u += 0x7fffu + ((u >> 16) & 1u);
  return (ushort_t)(u >> 16);
}

__device__ __forceinline__ void gload16(const void* g, void* l) {
  __builtin_amdgcn_global_load_lds((const __attribute__((address_space(1))) void*)g,
                                   (__attribute__((address_space(3))) void*)l, 16, 0, 0);
}

// ---------------- convert fp32 -> bf16: x + Wq|Wk|Wv (contiguous) ----------
__global__ void convert4_kernel(const float* __restrict__ x,
                                const float* __restrict__ wq, const float* __restrict__ wk,
                                const float* __restrict__ wv,
                                ushort_t* __restrict__ xb, ushort_t* __restrict__ wcat) {
  const float* src; ushort_t* dst; int n;
  switch (blockIdx.y) {
    case 0: src = x;  dst = xb;             n = NROW * D_DIM;  break;
    case 1: src = wq; dst = wcat;           n = D_DIM * D_DIM; break;
    case 2: src = wk; dst = wcat + 1048576; n = D_DIM * D_DIM; break;
    default: src = wv; dst = wcat + 2097152; n = D_DIM * D_DIM; break;
  }
  int base = (blockIdx.x * 256 + threadIdx.x) * 8;
  if (base >= n) return;
  f32x4 va = *(const f32x4*)(src + base);
  f32x4 vb = *(const f32x4*)(src + base + 4);
  short8 o;
  o[0] = (short)f2bf(va[0]); o[1] = (short)f2bf(va[1]);
  o[2] = (short)f2bf(va[2]); o[3] = (short)f2bf(va[3]);
  o[4] = (short)f2bf(vb[0]); o[5] = (short)f2bf(vb[1]);
  o[6] = (short)f2bf(vb[2]); o[7] = (short)f2bf(vb[3]);
  *(short8*)(dst + base) = o;
}

__global__ void convert_wo_kernel(const float* __restrict__ wo, ushort_t* __restrict__ wob) {
  int base = (blockIdx.x * 256 + threadIdx.x) * 8;
  f32x4 va = *(const f32x4*)(wo + base);
  f32x4 vb = *(const f32x4*)(wo + base + 4);
  short8 o;
  o[0] = (short)f2bf(va[0]); o[1] = (short)f2bf(va[1]);
  o[2] = (short)f2bf(va[2]); o[3] = (short)f2bf(va[3]);
  o[4] = (short)f2bf(vb[0]); o[5] = (short)f2bf(vb[1]);
  o[6] = (short)f2bf(vb[2]); o[7] = (short)f2bf(vb[3]);
  *(short8*)(wob + base) = o;
}

// ---------------- GEMM with global_load_lds staging (m97 structure) --------
// A[4096,1024]*Bw[NB,1024]^T. MODE 0: merged QKV epilogue (NB=3072), with
// K and V^T written PRE-SWIZZLED (XOR granule swizzle) so the attention
// kernel can stage them linearly via global_load_lds and read conflict-free.
// MODE 2: fp32 row-major out (NB=1024).
template<int MODE>
__global__ __launch_bounds__(256, 4) void gemm_glds(const ushort_t* __restrict__ A,
                                                    const ushort_t* __restrict__ Bw,
                                                    const float* __restrict__ bias0,
                                                    const float* __restrict__ bias1,
                                                    const float* __restrict__ bias2,
                                                    void* __restrict__ Cout) {
  __shared__ ushort_t As[128 * 64];
  __shared__ ushort_t Bs[128 * 64];
  const int t = threadIdx.x;
  const int lane = t & 63;
  const int w = t >> 6;
  const int wm = w >> 1, wn = w & 1;
  const int m0 = blockIdx.x * 128, n0 = blockIdx.y * 128;
  const int g = lane >> 4, c0 = lane & 15;
  const int srow = lane >> 3, scol = (lane & 7) * 8;

  f32x4 acc[4][4] = {};

  for (int kt = 0; kt < 16; ++kt) {
    const int kk = kt * 64;
#pragma unroll
    for (int i = 0; i < 4; ++i) {
      gload16(A  + (size_t)(m0 + w * 32 + i * 8 + srow) * D_DIM + kk + scol, &As[(w * 32 + i * 8) * 64]);
      gload16(Bw + (size_t)(n0 + w * 32 + i * 8 + srow) * D_DIM + kk + scol, &Bs[(w * 32 + i * 8) * 64]);
    }
    asm volatile("s_waitcnt vmcnt(0)" ::: "memory");
    __syncthreads();
#pragma unroll
    for (int kc = 0; kc < 2; ++kc) {
      short8 af[4], bf[4];
#pragma unroll
      for (int mf = 0; mf < 4; ++mf)
        af[mf] = *(const short8*)&As[(wm * 64 + mf * 16 + c0) * 64 + kc * 32 + g * 8];
#pragma unroll
      for (int nf = 0; nf < 4; ++nf)
        bf[nf] = *(const short8*)&Bs[(wn * 64 + nf * 16 + c0) * 64 + kc * 32 + g * 8];
#pragma unroll
      for (int mf = 0; mf < 4; ++mf)
#pragma unroll
        for (int nf = 0; nf < 4; ++nf)
          acc[mf][nf] = __builtin_amdgcn_mfma_f32_16x16x32_bf16(af[mf], bf[nf], acc[mf][nf], 0, 0, 0);
    }
    __syncthreads();
  }

#pragma unroll
  for (int nf = 0; nf < 4; ++nf) {
    int jj = n0 + wn * 64 + nf * 16 + c0;
    float bval;
    if (MODE == 0) {
      int proj = jj >> 10, jcol = jj & 1023;
      const float* bp = (proj == 0) ? bias0 : ((proj == 1) ? bias1 : bias2);
      bval = bp[jcol];
    } else {
      bval = bias0[jj];
    }
#pragma unroll
    for (int mf = 0; mf < 4; ++mf) {
#pragma unroll
      for (int r = 0; r < 4; ++r) {
        int ii = m0 + wm * 64 + mf * 16 + g * 4 + r;
        float v = acc[mf][nf][r] + bval;
        if (MODE == 2) {
          ((float*)Cout)[(size_t)ii * D_DIM + jj] = v;
        } else {
          int proj = jj >> 10, jcol = jj & 1023;
          if (proj == 0) v *= 0.125f;                    // fold sm_scale into Q
          int bb = ii >> 11, s = ii & 2047;
          size_t addr;
          if (proj == 0) {
            int hcol = jcol >> 6, hd = jcol & 63;
            addr = ((size_t)(bb * 16 + hcol) * 2048 + s) * 64 + hd;
          } else if (proj == 1) {
            // K pre-swizzled: granule bits [5:3] of hd XOR'd with s&7
            int hcol = jcol >> 6, hd = jcol & 63;
            addr = (size_t)4194304 + ((size_t)(bb * 16 + hcol) * 2048 + s) * 64
                 + (hd ^ ((s & 7) << 3));
          } else {
            // V^T pre-swizzled: granule bits [5:3] of s XOR'd with d&7
            addr = (size_t)8388608 + ((size_t)bb * 1024 + jcol) * 2048
                 + (s ^ ((jcol & 7) << 3));
          }
          ((ushort_t*)Cout)[addr] = f2bf(v);
        }
      }
    }
  }
}

// ---------------- fused masked attention -----------------------------------
// r5 shape: 8 waves x 16q = 128-q tile, kv 64, double-buffered, grid 512.
// New: K/V staged via global_load_lds (linear LDS; global pre-swizzled, reads
// XOR-deswizzle -> conflict-light), counted vmcnt + raw s_barrier (1/iter),
// setprio around MFMA clusters, 4-way denominator chains.
__global__ __launch_bounds__(512, 4) void attn_kernel(const ushort_t* __restrict__ Qg,
                                                      const ushort_t* __restrict__ Kg,
                                                      const ushort_t* __restrict__ Vtg,
                                                      const float* __restrict__ Mg,
                                                      ushort_t* __restrict__ aout) {
  __shared__ ushort_t Ks[2][64 * 64];
  __shared__ ushort_t Vts[2][64 * 64];

  const int t = threadIdx.x, lane = t & 63, w = t >> 6;   // 8 waves
  const int g = lane >> 4, c0 = lane & 15;
  const int id = blockIdx.x;
  const int r8 = id & 7, hh = (id >> 3) & 15, ss = id >> 7;
  const int combo = r8 + 8 * ss, b = combo >> 4, q0 = (combo & 15) * 128;
  const int bh = b * 16 + hh;

  const ushort_t* Qbase = Qg + ((size_t)bh * 2048 + q0) * 64;
  const float*    Mbase = Mg + ((size_t)b * 2048 + q0 + w * 16 + c0) * 2048 + g * 4;

  // per-lane staging sources (linear copy of pre-swizzled global K / V^T)
  const ushort_t* Ksrc = Kg  + (size_t)bh * 2048 * 64
                       + ((size_t)(w * 8 + (lane >> 3)) * 64 + (lane & 7) * 8);
  const ushort_t* Vsrc = Vtg + (size_t)bh * 64 * 2048
                       + ((size_t)(w * 8 + (lane >> 3)) * 2048 + (lane & 7) * 8);

  short8 qf[2];
#pragma unroll
  for (int kc = 0; kc < 2; ++kc)
    qf[kc] = *(const short8*)(Qbase + (size_t)(w * 16 + c0) * 64 + kc * 32 + g * 8);

  f32x4 o[4] = {};
  f32x4 dpev = {0.f, 0.f, 0.f, 0.f};
  const int swz = (c0 & 7) << 3;                 // read-side deswizzle
  const int idxA = (((g & 1) * 2 + (g >> 1)) * 16 + c0) * 4;
  const int idxB = (((g & 1) * 2 + 1 - (g >> 1)) * 16 + c0) * 4;
  const bool glo = (g < 2);
  const bool gb = (g & 1);

#define STAGE(kt_, buf_) { \
    gload16(Ksrc + (size_t)(kt_) * 4096, &Ks[buf_][w * 512]); \
    gload16(Vsrc + (size_t)(kt_) * 64,   &Vts[buf_][w * 512]); }

  // prologue: tile 0 + M(0)
  STAGE(0, 0);
  f32x4 rm[4];
#pragma unroll
  for (int nf = 0; nf < 4; ++nf) rm[nf] = *(const f32x4*)(Mbase + nf * 16);
  asm volatile("s_waitcnt vmcnt(0)" ::: "memory");
  __builtin_amdgcn_s_barrier();
  __builtin_amdgcn_sched_barrier(0);

  for (int kt = 0; kt < 32; ++kt) {
    const int cur = kt & 1;
    f32x4 rmn[4];
    if (kt < 31) {
      STAGE(kt + 1, cur ^ 1);                    // 2 gload_lds (oldest vmem)
      __builtin_amdgcn_sched_barrier(0);         // pin: staging before M loads
      const float* Mk = Mbase + (size_t)(kt + 1) * 64;
#pragma unroll
      for (int nf = 0; nf < 4; ++nf) rmn[nf] = *(const f32x4*)(Mk + nf * 16);
    }

    // QK^T swapped: sf[nf][r] = S[k = nf*16 + g*4 + r][q = c0]
    f32x4 sf[4] = {};
    __builtin_amdgcn_s_setprio(1);
#pragma unroll
    for (int kc = 0; kc < 2; ++kc) {
      short8 kf[4];
#pragma unroll
      for (int nf = 0; nf < 4; ++nf)
        kf[nf] = *(const short8*)&Ks[cur][(nf * 16 + c0) * 64 + ((kc * 32 + g * 8) ^ swz)];
#pragma unroll
      for (int nf = 0; nf < 4; ++nf)
        sf[nf] = __builtin_amdgcn_mfma_f32_16x16x32_bf16(kf[nf], qf[kc], sf[nf], 0, 0, 0);
    }
    __builtin_amdgcn_s_setprio(0);

    // mask * exp ; pack P to bf16 pairs (k-adjacent within lane)
    uint32_t w4[4][2];
#pragma unroll
    for (int nf = 0; nf < 4; ++nf) {
      float p[4];
#pragma unroll
      for (int r = 0; r < 4; ++r) {
        float m = rm[nf][r];
        float e = __expf(sf[nf][r] * m);
        float pe = m * e;
        dpev[r] += pe;
        p[r] = pe;
      }
      asm("v_cvt_pk_bf16_f32 %0, %1, %2" : "=v"(w4[nf][0]) : "v"(p[0]), "v"(p[1]));
      asm("v_cvt_pk_bf16_f32 %0, %1, %2" : "=v"(w4[nf][1]) : "v"(p[2]), "v"(p[3]));
    }

    // redistribute: lane needs P[q=c0][k = kc*32 + g*8 + j]
    short8 pf[2];
#pragma unroll
    for (int kc = 0; kc < 2; ++kc) {
      uint32_t sA0 = gb ? w4[2 * kc + 1][0] : w4[2 * kc][0];
      uint32_t sA1 = gb ? w4[2 * kc + 1][1] : w4[2 * kc][1];
      uint32_t sB0 = gb ? w4[2 * kc][0]     : w4[2 * kc + 1][0];
      uint32_t sB1 = gb ? w4[2 * kc][1]     : w4[2 * kc + 1][1];
      uint32_t rA0 = (uint32_t)__builtin_amdgcn_ds_bpermute(idxA, (int)sA0);
      uint32_t rA1 = (uint32_t)__builtin_amdgcn_ds_bpermute(idxA, (int)sA1);
      uint32_t rB0 = (uint32_t)__builtin_amdgcn_ds_bpermute(idxB, (int)sB0);
      uint32_t rB1 = (uint32_t)__builtin_amdgcn_ds_bpermute(idxB, (int)sB1);
      i32x4 f4;
      f4[0] = (int)(glo ? rA0 : rB0);
      f4[1] = (int)(glo ? rA1 : rB1);
      f4[2] = (int)(glo ? rB0 : rA0);
      f4[3] = (int)(glo ? rB1 : rA1);
      pf[kc] = __builtin_bit_cast(short8, f4);
    }

    // PV: o^T[d][q] += sum_k V[k][d] * P[q][k]
    __builtin_amdgcn_s_setprio(1);
#pragma unroll
    for (int kc = 0; kc < 2; ++kc) {
#pragma unroll
      for (int df = 0; df < 4; ++df) {
        short8 vf = *(const short8*)&Vts[cur][(df * 16 + c0) * 64 + ((kc * 32 + g * 8) ^ swz)];
        o[df] = __builtin_amdgcn_mfma_f32_16x16x32_bf16(vf, pf[kc], o[df], 0, 0, 0);
      }
    }
    __builtin_amdgcn_s_setprio(0);

    if (kt < 31) {
      // own staging (oldest 2) retired; M loads (youngest 4) may keep flying
      asm volatile("s_waitcnt vmcnt(4)" ::: "memory");
      __builtin_amdgcn_s_barrier();
      __builtin_amdgcn_sched_barrier(0);
#pragma unroll
      for (int nf = 0; nf < 4; ++nf) rm[nf] = rmn[nf];
    }
  }

  // denominator: in-lane 4 chains, then across the 4 g-groups (same q = c0)
  float dpe = (dpev[0] + dpev[1]) + (dpev[2] + dpev[3]);
  dpe += __shfl_xor(dpe, 16);
  dpe += __shfl_xor(dpe, 32);
  float inv = 1.0f / dpe;

  // write O^T fragment: lane has O[d = df*16 + g*4 + r][q = c0]
#pragma unroll
  for (int df = 0; df < 4; ++df) {
    float v0 = o[df][0] * inv, v1 = o[df][1] * inv;
    float v2 = o[df][2] * inv, v3 = o[df][3] * inv;
    uint32_t d0, d1;
    asm("v_cvt_pk_bf16_f32 %0, %1, %2" : "=v"(d0) : "v"(v0), "v"(v1));
    asm("v_cvt_pk_bf16_f32 %0, %1, %2" : "=v"(d1) : "v"(v2), "v"(v3));
    unsigned long long pk = (unsigned long long)d0 | ((unsigned long long)d1 << 32);
    *(unsigned long long*)&aout[((size_t)b * 2048 + q0 + w * 16 + c0) * 1024 + hh * 64 + df * 16 + g * 4] = pk;
  }
#undef STAGE
}

// ---------------------------------------------------------------------------
extern "C" void kernel_launch(void* const* d_in, const int* in_sizes, int n_in,
                              void* d_out, int out_size, void* d_ws, size_t ws_size,
                              hipStream_t stream) {
  const float* x  = (const float*)d_in[0];
  const float* M  = (const float*)d_in[1];
  const float* Wq = (const float*)d_in[2];
  const float* bq = (const float*)d_in[3];
  const float* Wk = (const float*)d_in[4];
  const float* bk = (const float*)d_in[5];
  const float* Wv = (const float*)d_in[6];
  const float* bv = (const float*)d_in[7];
  const float* Wo = (const float*)d_in[8];
  const float* bo = (const float*)d_in[9];
  float* out = (float*)d_out;
  char* ws = (char*)d_ws;

  ushort_t* Qb    = (ushort_t*)(ws);               // 8MB   [qkv-gemm .. attn]
  ushort_t* Kb    = (ushort_t*)(ws + 8388608);     // 8MB   (pre-swizzled)
  ushort_t* Vtb   = (ushort_t*)(ws + 16777216);    // 8MB   (pre-swizzled)
  ushort_t* xb    = (ushort_t*)(ws + 25165824);    // 8MB   [convert .. qkv-gemm]
  ushort_t* Wcat  = (ushort_t*)(ws + 33554432);    // 6MB   [convert .. qkv-gemm]
  ushort_t* aoutb = (ushort_t*)(ws + 41943040);    // 8MB   [attn .. out-gemm]
  ushort_t* wob   = (ushort_t*)(ws + 39845888);    // 2MB   [anytime; below aoutb]

  convert4_kernel<<<dim3(2048, 4), 256, 0, stream>>>(x, Wq, Wk, Wv, xb, Wcat);
  convert_wo_kernel<<<512, 256, 0, stream>>>(Wo, wob);
  gemm_glds<0><<<dim3(32, 24), 256, 0, stream>>>(xb, Wcat, bq, bk, bv, (void*)Qb);
  attn_kernel<<<512, 512, 0, stream>>>(Qb, Kb, Vtb, M, aoutb);
  gemm_glds<2><<<dim3(32, 8), 256, 0, stream>>>(aoutb, wob, bo, bo, bo, (void*)out);
}